// Round 10
// baseline (176.444 us; speedup 1.0000x reference)
//
#include <hip/hip_runtime.h>
#include <math.h>

typedef __attribute__((ext_vector_type(8))) short bf16x8;
typedef __attribute__((ext_vector_type(4))) float f32x4;
#define MFMA16(a, b, c) __builtin_amdgcn_mfma_f32_16x16x32_bf16(a, b, c, 0, 0, 0)

union U8 { bf16x8 v; unsigned i4[4]; };

__device__ __forceinline__ unsigned short f2bf(float x) {
    unsigned u = __builtin_bit_cast(unsigned, x);
    unsigned r = (u + 0x7fffu + ((u >> 16) & 1u)) >> 16;   // RNE
    return (unsigned short)r;
}
// packed RNE f32x2 -> bf16x2 (dst.lo = cvt(src0), dst.hi = cvt(src1))
__device__ __forceinline__ unsigned cvtpk(float lo, float hi) {
    unsigned r;
    asm("v_cvt_pk_bf16_f32 %0, %1, %2" : "=v"(r) : "v"(lo), "v"(hi));
    return r;
}

// conv1 K-permutation sigma (same on A and B, cancels):
__device__ __forceinline__ int koff_of(int kidx) {
    int grp = kidx >> 3, e = kidx & 7;
    if (grp < 9)  return grp * 9 + e;
    if (grp == 9) return e * 9 + 8;
    if (grp == 10) return (e == 0) ? 80 : -1;
    return -1;
}

#define CAPS_BYTES 37748736
#define A1F_ELEMS  24576
#define W3F_ELEMS  82944    // 81 taps * 2 m * 64 lanes * 8 e
#define WBF_ELEMS  147456   // 1152 * 8 * 16 bf16 copy of dig_W

// ---------------------------------------------------------------------------
// K0: pack conv weights into MFMA fragment layout + dig_W -> bf16
// ---------------------------------------------------------------------------
__global__ void k_prep(const float* __restrict__ c1w,  // [256,1,9,9]
                       const float* __restrict__ pw,   // [32,32,1,9,9]
                       const float* __restrict__ digW, // [1152,8,16]
                       unsigned short* __restrict__ w1f,
                       unsigned short* __restrict__ w3f,
                       unsigned short* __restrict__ wbf)
{
    int idx = blockIdx.x * 256 + threadIdx.x;
    if (idx < A1F_ELEMS) {
        int e = idx & 7, lane = (idx >> 3) & 63, f = idx >> 9;
        int k3 = f % 3, m = (f / 3) & 1, d = f / 6;
        int ch = (lane & 15) + m * 16;
        int kidx = k3 * 32 + ((lane >> 4) << 3) + e;
        int ko = koff_of(kidx);
        w1f[idx] = f2bf(ko >= 0 ? c1w[(ch * 8 + d) * 81 + ko] : 0.f);
    } else if (idx < A1F_ELEMS + W3F_ELEMS) {
        int j = idx - A1F_ELEMS;
        int e = j & 7, lane = (j >> 3) & 63, f = j >> 9;
        int m = f & 1, tap = f >> 1;
        int oc = (lane & 15) + m * 16;
        int i = ((lane >> 4) << 3) + e;
        w3f[j] = f2bf(pw[oc * 2592 + i * 81 + tap]);
    } else if (idx < A1F_ELEMS + W3F_ELEMS + WBF_ELEMS) {
        int j = idx - A1F_ELEMS - W3F_ELEMS;
        wbf[j] = f2bf(digW[j]);
    }
}

// ---------------------------------------------------------------------------
// K1: fused conv1 + prim conv. One block = one (b,d) slice. 4 blocks/CU.
// Phase-1 image gathers: f32 img in even/odd shifted copies (stride 808 ->
// copies 8 banks apart) -> 4 aligned ds_read_b64 per frag + cvt_pk. This
// replaces the 2B-aligned overlapping b32 unions (the conflict source).
// Phase 2 (R7-best): linear [pos][ch40] interm, row-split taps, offsets as
// compile-time immediates.
// ---------------------------------------------------------------------------
__global__ __launch_bounds__(256, 4) void k_conv(
    const float* __restrict__ x,    // [1024,1,28,28]
    const float* __restrict__ c1b,  // [256]
    const float* __restrict__ pb,   // [32]
    const unsigned short* __restrict__ w1f,
    const unsigned short* __restrict__ w3f,
    float* __restrict__ caps)       // [1024,8,1152]
{
    __shared__ __align__(16) float img_f[2 * 808];              //  6464 B
    __shared__ __align__(128) unsigned short interm[400 * 40];  // 32000 B

    const int t = threadIdx.x;
    const int lane = t & 63, w = t >> 6;
    const int g = lane >> 4, col = lane & 15;
    const int b = blockIdx.x >> 3, d = blockIdx.x & 7;

    for (int idx = t; idx < 784; idx += 256) {
        float v = x[b * 784 + idx];
        img_f[idx] = v;
        if (idx > 0) img_f[808 + idx - 1] = v;   // shifted-by-1 copy
    }
    __syncthreads();

    // =================== phase 1: conv1 ===================
    {
        bf16x8 a1[2][3];
        const bf16x8* w1p = (const bf16x8*)w1f;
#pragma unroll
        for (int m = 0; m < 2; ++m)
#pragma unroll
            for (int k3 = 0; k3 < 3; ++k3)
                a1[m][k3] = w1p[((d * 2 + m) * 3 + k3) * 64 + lane];

        float bias[2][4];
#pragma unroll
        for (int m = 0; m < 2; ++m)
#pragma unroll
            for (int r = 0; r < 4; ++r)
                bias[m][r] = c1b[(m * 16 + g * 4 + r) * 8 + d];

        const int g28 = g * 28;

        for (int q = w; q < 25; q += 4) {
            int p = q * 16 + col;
            int py = p / 20, px = p - py * 20;
            int base = py * 28 + px;
            int par = base & 1;
            const float* tb = img_f + par * 808 + (base - par);  // even f32 index -> 8B aligned

            bf16x8 bfrag[3];
#pragma unroll
            for (int k3 = 0; k3 < 2; ++k3) {
                const float2* rp2 = (const float2*)(tb + k3 * 112 + g28);
                float2 f01 = rp2[0], f23 = rp2[1], f45 = rp2[2], f67 = rp2[3];
                U8 u8;
                u8.i4[0] = cvtpk(f01.x, f01.y);
                u8.i4[1] = cvtpk(f23.x, f23.y);
                u8.i4[2] = cvtpk(f45.x, f45.y);
                u8.i4[3] = cvtpk(f67.x, f67.y);
                bfrag[k3] = u8.v;
            }
            {
                U8 u8;
                if (g == 0) {
                    const float2* rp2 = (const float2*)(tb + 224);
                    float2 f01 = rp2[0], f23 = rp2[1], f45 = rp2[2], f67 = rp2[3];
                    u8.i4[0] = cvtpk(f01.x, f01.y);
                    u8.i4[1] = cvtpk(f23.x, f23.y);
                    u8.i4[2] = cvtpk(f45.x, f45.y);
                    u8.i4[3] = cvtpk(f67.x, f67.y);
                } else if (g == 1) {
                    float f[8];
#pragma unroll
                    for (int e = 0; e < 8; ++e)
                        f[e] = img_f[base + e * 28 + 8];
                    u8.i4[0] = cvtpk(f[0], f[1]);
                    u8.i4[1] = cvtpk(f[2], f[3]);
                    u8.i4[2] = cvtpk(f[4], f[5]);
                    u8.i4[3] = cvtpk(f[6], f[7]);
                } else if (g == 2) {
                    float v = img_f[base + 8 * 28 + 8];
                    u8.i4[0] = cvtpk(v, 0.f);
                    u8.i4[1] = 0; u8.i4[2] = 0; u8.i4[3] = 0;
                } else {
                    u8.i4[0] = 0; u8.i4[1] = 0; u8.i4[2] = 0; u8.i4[3] = 0;
                }
                bfrag[2] = u8.v;
            }

            f32x4 acc0 = {0.f, 0.f, 0.f, 0.f};
            f32x4 acc1 = {0.f, 0.f, 0.f, 0.f};
#pragma unroll
            for (int k3 = 0; k3 < 3; ++k3) {
                acc0 = MFMA16(a1[0][k3], bfrag[k3], acc0);
                acc1 = MFMA16(a1[1][k3], bfrag[k3], acc1);
            }
            float r0[4], r1[4];
#pragma unroll
            for (int r = 0; r < 4; ++r) {
                r0[r] = fmaxf(acc0[r] + bias[0][r], 0.f);
                r1[r] = fmaxf(acc1[r] + bias[1][r], 0.f);
            }
            *(uint2*)(&interm[p * 40 + g * 4])      = make_uint2(cvtpk(r0[0], r0[1]), cvtpk(r0[2], r0[3]));
            *(uint2*)(&interm[p * 40 + 16 + g * 4]) = make_uint2(cvtpk(r1[0], r1[1]), cvtpk(r1[2], r1[3]));
        }
    }
    __syncthreads();

    // =================== phase 2: prim conv, row-split by wave ===================
    f32x4 acc[2][3];
#pragma unroll
    for (int m = 0; m < 2; ++m)
#pragma unroll
        for (int nt = 0; nt < 3; ++nt)
            acc[m][nt] = (f32x4){0.f, 0.f, 0.f, 0.f};
    {
        int abase[3];   // byte base per nt: pos0*80 + g*16
#pragma unroll
        for (int nt = 0; nt < 3; ++nt) {
            int p2 = nt * 16 + col;
            int xw = p2 / 6, yh = p2 - xw * 6;
            int pos0 = (p2 < 36) ? (yh * 40 + xw * 2) : 0;
            abase[nt] = pos0 * 80 + g * 16;
        }
        const bf16x8* w3p = (const bf16x8*)w3f;
        const char* ib = (const char*)interm;

        for (int rr = 0; rr < 2; ++rr) {
            const int ky = 2 * w + rr;
            const bf16x8* wrow = w3p + (ky * 9) * 128;
            const char* B0 = ib + abase[0] + ky * 1600;
            const char* B1 = ib + abase[1] + ky * 1600;
            const char* B2 = ib + abase[2] + ky * 1600;
#pragma unroll
            for (int kx = 0; kx < 9; ++kx) {
                bf16x8 a0  = wrow[kx * 128 + lane];
                bf16x8 a1v = wrow[kx * 128 + 64 + lane];
                bf16x8 b0 = *(const bf16x8*)(B0 + kx * 80);
                bf16x8 b1 = *(const bf16x8*)(B1 + kx * 80);
                bf16x8 b2 = *(const bf16x8*)(B2 + kx * 80);
                acc[0][0] = MFMA16(a0, b0, acc[0][0]);
                acc[1][0] = MFMA16(a1v, b0, acc[1][0]);
                acc[0][1] = MFMA16(a0, b1, acc[0][1]);
                acc[1][1] = MFMA16(a1v, b1, acc[1][1]);
                acc[0][2] = MFMA16(a0, b2, acc[0][2]);
                acc[1][2] = MFMA16(a1v, b2, acc[1][2]);
            }
        }
        // row 8 leftovers: w0:{0,1} w1:{2,3} w2:{4,5} w3:{6,7,8}
        {
            const bf16x8* wrow = w3p + 72 * 128;
            const char* B0 = ib + abase[0] + 12800;
            const char* B1 = ib + abase[1] + 12800;
            const char* B2 = ib + abase[2] + 12800;
            int kx0 = 2 * w;
            int nkx = (w == 3) ? 3 : 2;
#pragma unroll 3
            for (int q = 0; q < nkx; ++q) {
                int kx = kx0 + q;
                bf16x8 a0  = wrow[kx * 128 + lane];
                bf16x8 a1v = wrow[kx * 128 + 64 + lane];
                bf16x8 b0 = *(const bf16x8*)(B0 + kx * 80);
                bf16x8 b1 = *(const bf16x8*)(B1 + kx * 80);
                bf16x8 b2 = *(const bf16x8*)(B2 + kx * 80);
                acc[0][0] = MFMA16(a0, b0, acc[0][0]);
                acc[1][0] = MFMA16(a1v, b0, acc[1][0]);
                acc[0][1] = MFMA16(a0, b1, acc[0][1]);
                acc[1][1] = MFMA16(a1v, b1, acc[1][1]);
                acc[0][2] = MFMA16(a0, b2, acc[0][2]);
                acc[1][2] = MFMA16(a1v, b2, acc[1][2]);
            }
        }
    }
    __syncthreads();
    // ---- cross-wave reduction (f32x4 overlay on interm) ----
    f32x4* rp = (f32x4*)&interm[0];
    {
#pragma unroll
        for (int m = 0; m < 2; ++m)
#pragma unroll
            for (int nt = 0; nt < 3; ++nt)
                rp[(w * 6 + m * 3 + nt) * 64 + lane] = acc[m][nt];
    }
    __syncthreads();
    for (int idx = t; idx < 384; idx += 256) {
        int tile = idx >> 6, ls = idx & 63;
        f32x4 s = rp[tile * 64 + ls];
#pragma unroll
        for (int ww = 1; ww < 4; ++ww)
            s += rp[(ww * 6 + tile) * 64 + ls];
        int m = tile / 3, nt = tile - m * 3;
        int p2 = nt * 16 + (ls & 15);
        if (p2 < 36) {
            int gr = ls >> 4;
#pragma unroll
            for (int r = 0; r < 4; ++r) {
                int oc = m * 16 + gr * 4 + r;
                caps[(b * 8 + d) * 1152 + oc * 36 + p2] = fmaxf(s[r] + pb[oc], 0.f);
            }
        }
    }
}

// ---------------------------------------------------------------------------
// K2: routing (R9 measured-best). 576 threads, ~50.3 KB LDS -> 3 blocks/CU.
// ---------------------------------------------------------------------------
#define USB 1160   // u_bf row stride (bf16)
#define CHS 584    // chalf row stride (bf16)

__global__ __launch_bounds__(576, 8) void k_route(
    const float* __restrict__ caps,  // [1024,8,1152]
    const unsigned short* __restrict__ Wbf,  // [1152,8,16] bf16
    const float* __restrict__ Wb,    // [1152,16]
    const float* __restrict__ ow,    // [10,10,16,1]
    const float* __restrict__ ob,    // [10]
    float* __restrict__ out)         // [1024,10]
{
    __shared__ __align__(16) unsigned short u_bf[16 * USB];   // 37,120 B
    __shared__ __align__(16) unsigned short chalf[10 * CHS];  // 11,680 B (+scratch overlay)
    __shared__ __align__(16) float vv[16 * 12];
    __shared__ float ss[160];
    __shared__ float red2[16];

    const int t = threadIdx.x;
    const int lane = t & 63, wv = t >> 6;
    const int g = lane >> 4, col = lane & 15;
    const int b = blockIdx.x;
    const int n0 = 2 * t;

    // ---- stage A: u[f][n] -> bf16 (W streamed as bf16) ----
    {
        const int nl = t >> 2, fq = t & 3;
        for (int base = 0; base < 1152; base += 144) {
            int n = base + nl;
            float cv[8];
#pragma unroll
            for (int e = 0; e < 8; ++e) cv[e] = caps[(b * 8 + e) * 1152 + n];
            float4 a4 = ((const float4*)(Wb + n * 16))[fq];
#pragma unroll
            for (int e = 0; e < 8; ++e) {
                uint2 wp = *(const uint2*)(&Wbf[n * 128 + e * 16 + fq * 4]);
                float w0 = __builtin_bit_cast(float, wp.x << 16);
                float w1 = __builtin_bit_cast(float, wp.x & 0xffff0000u);
                float w2 = __builtin_bit_cast(float, wp.y << 16);
                float w3 = __builtin_bit_cast(float, wp.y & 0xffff0000u);
                a4.x += cv[e] * w0; a4.y += cv[e] * w1;
                a4.z += cv[e] * w2; a4.w += cv[e] * w3;
            }
            u_bf[(fq * 4 + 0) * USB + n] = f2bf(a4.x);
            u_bf[(fq * 4 + 1) * USB + n] = f2bf(a4.y);
            u_bf[(fq * 4 + 2) * USB + n] = f2bf(a4.z);
            u_bf[(fq * 4 + 3) * USB + n] = f2bf(a4.w);
        }
    }
    float breg[2][10];
#pragma unroll
    for (int s = 0; s < 2; ++s)
#pragma unroll
        for (int jj = 0; jj < 10; ++jj) breg[s][jj] = 0.f;
    __syncthreads();

    const int jrow = (col < 10) ? col : 9;
    const int hmine = (t >= 288);
    const int nh = 2 * t - 576 * hmine;

    for (int iter = 0; iter < 3; ++iter) {
        // ---- softmax over j for n0,n0+1 -> packed bf16 pairs (registers) ----
        unsigned pk[10];
        {
            float cv2[2][10];
#pragma unroll
            for (int s = 0; s < 2; ++s) {
                float m = breg[s][0];
#pragma unroll
                for (int jj = 1; jj < 10; ++jj) m = fmaxf(m, breg[s][jj]);
                float sum = 0.f;
#pragma unroll
                for (int jj = 0; jj < 10; ++jj) { cv2[s][jj] = __expf(breg[s][jj] - m); sum += cv2[s][jj]; }
                float inv = 1.f / sum;
#pragma unroll
                for (int jj = 0; jj < 10; ++jj) cv2[s][jj] *= inv;
            }
#pragma unroll
            for (int jj = 0; jj < 10; ++jj)
                pk[jj] = cvtpk(cv2[0][jj], cv2[1][jj]);
        }

        // ---- stage B+C over two n-halves; sp accumulates in registers ----
        f32x4 sp = {0.f, 0.f, 0.f, 0.f};
#pragma unroll
        for (int h = 0; h < 2; ++h) {
            if (hmine == h) {
#pragma unroll
                for (int jj = 0; jj < 10; ++jj)
                    *(unsigned*)(&chalf[jj * CHS + nh]) = pk[jj];
            }
            __syncthreads();
#pragma unroll
            for (int mf = 0; mf < 2; ++mf) {
                int nk = wv * 64 + mf * 32 + g * 8;
                bf16x8 af = *(const bf16x8*)(&chalf[jrow * CHS + nk]);
                bf16x8 bf = *(const bf16x8*)(&u_bf[col * USB + h * 576 + nk]);
                sp = MFMA16(af, bf, sp);
            }
            __syncthreads();
        }
        // ---- partials -> scratch (overlays chalf) ----
        float* scratch = (float*)chalf;
        *(f32x4*)(&scratch[(wv * 64 + lane) * 4]) = sp;
        __syncthreads();
        if (t < 160) {
            int j = t >> 4, f = t & 15;
            int li = ((j >> 2) * 16 + f) * 4 + (j & 3);
            float s = 0.f;
#pragma unroll
            for (int ww = 0; ww < 9; ++ww) s += scratch[ww * 256 + li];
            ss[j * 16 + f] = s;
        }
        __syncthreads();
        if (t < 16) {
            float sv[10], l2 = 0.f, l1 = 0.f;
#pragma unroll
            for (int jj = 0; jj < 10; ++jj) {
                sv[jj] = ss[jj * 16 + t];
                l2 += sv[jj] * sv[jj]; l1 += fabsf(sv[jj]);
            }
            l2 = sqrtf(l2);
            float scale = l2 / (1.f + l2) / l1;
#pragma unroll
            for (int jj = 0; jj < 10; ++jj) vv[t * 12 + jj] = sv[jj] * scale;
        }
        __syncthreads();
        if (iter < 2) {
#pragma unroll
            for (int f = 0; f < 16; ++f) {
                unsigned pair = *(const unsigned*)(&u_bf[f * USB + n0]);
                float ux = __builtin_bit_cast(float, pair << 16);
                float uy = __builtin_bit_cast(float, pair & 0xffff0000u);
                f32x4 v0 = *(const f32x4*)(&vv[f * 12]);
                f32x4 v1 = *(const f32x4*)(&vv[f * 12 + 4]);
                float2 v2 = *(const float2*)(&vv[f * 12 + 8]);
                breg[0][0] += ux * v0.x; breg[1][0] += uy * v0.x;
                breg[0][1] += ux * v0.y; breg[1][1] += uy * v0.y;
                breg[0][2] += ux * v0.z; breg[1][2] += uy * v0.z;
                breg[0][3] += ux * v0.w; breg[1][3] += uy * v0.w;
                breg[0][4] += ux * v1.x; breg[1][4] += uy * v1.x;
                breg[0][5] += ux * v1.y; breg[1][5] += uy * v1.y;
                breg[0][6] += ux * v1.z; breg[1][6] += uy * v1.z;
                breg[0][7] += ux * v1.w; breg[1][7] += uy * v1.w;
                breg[0][8] += ux * v2.x; breg[1][8] += uy * v2.x;
                breg[0][9] += ux * v2.y; breg[1][9] += uy * v2.y;
            }
        }
        __syncthreads();
    }

    // ---- output head + softmax ----
    if (t < 10) {
        float l = ob[t];
#pragma unroll
        for (int i2 = 0; i2 < 10; ++i2)
#pragma unroll
            for (int ff = 0; ff < 16; ++ff)
                l += vv[ff * 12 + i2] * ow[t * 160 + i2 * 16 + ff];
        red2[t] = l;
    }
    __syncthreads();
    if (t == 0) {
        float m = -1e30f;
        for (int o = 0; o < 10; ++o) m = fmaxf(m, red2[o]);
        float sum = 0.f; float e[10];
        for (int o = 0; o < 10; ++o) { e[o] = __expf(red2[o] - m); sum += e[o]; }
        float inv = 1.f / sum;
        for (int o = 0; o < 10; ++o) out[b * 10 + o] = e[o] * inv;
    }
}

extern "C" void kernel_launch(void* const* d_in, const int* in_sizes, int n_in,
                              void* d_out, int out_size, void* d_ws, size_t ws_size,
                              hipStream_t stream) {
    const float* x     = (const float*)d_in[0];
    const float* c1w   = (const float*)d_in[1];
    const float* c1b   = (const float*)d_in[2];
    const float* pw    = (const float*)d_in[3];
    const float* pb    = (const float*)d_in[4];
    const float* digW  = (const float*)d_in[5];
    const float* digWb = (const float*)d_in[6];
    const float* outw  = (const float*)d_in[7];
    const float* outb  = (const float*)d_in[8];
    float* out = (float*)d_out;

    float* caps = (float*)d_ws;
    unsigned short* w1f = (unsigned short*)((char*)d_ws + CAPS_BYTES);
    unsigned short* w3f = w1f + A1F_ELEMS;
    unsigned short* wbf = w3f + W3F_ELEMS;

    k_prep<<<dim3(996), dim3(256), 0, stream>>>(c1w, pw, digW, w1f, w3f, wbf);
    k_conv<<<dim3(8192), dim3(256), 0, stream>>>(x, c1b, pb, w1f, w3f, caps);
    k_route<<<dim3(1024), dim3(576), 0, stream>>>(caps, wbf, digWb, outw, outb, out);
}

// Round 11
// 169.293 us; speedup vs baseline: 1.0422x; 1.0422x over previous
//
#include <hip/hip_runtime.h>
#include <math.h>

typedef __attribute__((ext_vector_type(8))) short bf16x8;
typedef __attribute__((ext_vector_type(4))) float f32x4;
#define MFMA16(a, b, c) __builtin_amdgcn_mfma_f32_16x16x32_bf16(a, b, c, 0, 0, 0)

union U8 { bf16x8 v; int i4[4]; };

__device__ __forceinline__ unsigned short f2bf(float x) {
    unsigned u = __builtin_bit_cast(unsigned, x);
    unsigned r = (u + 0x7fffu + ((u >> 16) & 1u)) >> 16;   // RNE
    return (unsigned short)r;
}
// packed RNE f32x2 -> bf16x2
__device__ __forceinline__ unsigned cvtpk(float lo, float hi) {
    unsigned r;
    asm("v_cvt_pk_bf16_f32 %0, %1, %2" : "=v"(r) : "v"(lo), "v"(hi));
    return r;
}

// conv1 K-permutation sigma (same on A and B, cancels):
__device__ __forceinline__ int koff_of(int kidx) {
    int grp = kidx >> 3, e = kidx & 7;
    if (grp < 9)  return grp * 9 + e;
    if (grp == 9) return e * 9 + 8;
    if (grp == 10) return (e == 0) ? 80 : -1;
    return -1;
}

#define CAPS_BYTES 37748736
#define A1F_ELEMS  24576
#define W3F_ELEMS  82944    // 81 taps * 2 m * 64 lanes * 8 e
#define WBF_ELEMS  147456   // 1152 * 8 * 16 bf16 copy of dig_W

// ---------------------------------------------------------------------------
// K0: pack conv weights into MFMA fragment layout + dig_W -> bf16
// ---------------------------------------------------------------------------
__global__ void k_prep(const float* __restrict__ c1w,  // [256,1,9,9]
                       const float* __restrict__ pw,   // [32,32,1,9,9]
                       const float* __restrict__ digW, // [1152,8,16]
                       unsigned short* __restrict__ w1f,
                       unsigned short* __restrict__ w3f,
                       unsigned short* __restrict__ wbf)
{
    int idx = blockIdx.x * 256 + threadIdx.x;
    if (idx < A1F_ELEMS) {
        int e = idx & 7, lane = (idx >> 3) & 63, f = idx >> 9;
        int k3 = f % 3, m = (f / 3) & 1, d = f / 6;
        int ch = (lane & 15) + m * 16;
        int kidx = k3 * 32 + ((lane >> 4) << 3) + e;
        int ko = koff_of(kidx);
        w1f[idx] = f2bf(ko >= 0 ? c1w[(ch * 8 + d) * 81 + ko] : 0.f);
    } else if (idx < A1F_ELEMS + W3F_ELEMS) {
        int j = idx - A1F_ELEMS;
        int e = j & 7, lane = (j >> 3) & 63, f = j >> 9;
        int m = f & 1, tap = f >> 1;
        int oc = (lane & 15) + m * 16;
        int i = ((lane >> 4) << 3) + e;
        w3f[j] = f2bf(pw[oc * 2592 + i * 81 + tap]);
    } else if (idx < A1F_ELEMS + W3F_ELEMS + WBF_ELEMS) {
        int j = idx - A1F_ELEMS - W3F_ELEMS;
        wbf[j] = f2bf(digW[j]);
    }
}

// ---------------------------------------------------------------------------
// K1: fused conv1 + prim conv (R7/R9 measured-best variant, 110.5 us).
// Linear [pos][ch40] interm; bf16 img + shifted copy; row-split phase 2 with
// compile-time offsets. + s_setprio around phase-2 MFMA clusters (T5).
// 4 blocks/CU.
// ---------------------------------------------------------------------------
__global__ __launch_bounds__(256, 4) void k_conv(
    const float* __restrict__ x,    // [1024,1,28,28]
    const float* __restrict__ c1b,  // [256]
    const float* __restrict__ pb,   // [32]
    const unsigned short* __restrict__ w1f,
    const unsigned short* __restrict__ w3f,
    float* __restrict__ caps)       // [1024,8,1152]
{
    __shared__ __align__(16) unsigned short img[800];
    __shared__ __align__(16) unsigned short imgs[800];          // shifted by 1
    __shared__ __align__(128) unsigned short interm[400 * 40];  // 32000 B

    const int t = threadIdx.x;
    const int lane = t & 63, w = t >> 6;
    const int g = lane >> 4, col = lane & 15;
    const int b = blockIdx.x >> 3, d = blockIdx.x & 7;

    for (int idx = t; idx < 784; idx += 256) {
        unsigned short v = f2bf(x[b * 784 + idx]);
        img[idx] = v;
        if (idx > 0) imgs[idx - 1] = v;
    }
    __syncthreads();

    // =================== phase 1: conv1 ===================
    {
        bf16x8 a1[2][3];
        const bf16x8* w1p = (const bf16x8*)w1f;
#pragma unroll
        for (int m = 0; m < 2; ++m)
#pragma unroll
            for (int k3 = 0; k3 < 3; ++k3)
                a1[m][k3] = w1p[((d * 2 + m) * 3 + k3) * 64 + lane];

        float bias[2][4];
#pragma unroll
        for (int m = 0; m < 2; ++m)
#pragma unroll
            for (int r = 0; r < 4; ++r)
                bias[m][r] = c1b[(m * 16 + g * 4 + r) * 8 + d];

        for (int q = w; q < 25; q += 4) {
            int p = q * 16 + col;
            int py = p / 20, px = p - py * 20;
            int base = py * 28 + px;
            const unsigned short* rbase = (base & 1) ? &imgs[base - 1] : &img[base];

            bf16x8 bfrag[3];
#pragma unroll
            for (int k3 = 0; k3 < 2; ++k3) {
                int grp = k3 * 4 + g;
                U8 u8;
#pragma unroll
                for (int qq = 0; qq < 4; ++qq)
                    u8.i4[qq] = *(const int*)(rbase + grp * 28 + 2 * qq);
                bfrag[k3] = u8.v;
            }
            {
                U8 u8;
                if (g == 0) {
#pragma unroll
                    for (int qq = 0; qq < 4; ++qq)
                        u8.i4[qq] = *(const int*)(rbase + 8 * 28 + 2 * qq);
                } else if (g == 1) {
#pragma unroll
                    for (int e = 0; e < 8; ++e)
                        u8.v[e] = (short)img[base + e * 28 + 8];
                } else if (g == 2) {
                    u8.i4[0] = u8.i4[1] = u8.i4[2] = u8.i4[3] = 0;
                    u8.v[0] = (short)img[base + 8 * 28 + 8];
                } else {
                    u8.i4[0] = u8.i4[1] = u8.i4[2] = u8.i4[3] = 0;
                }
                bfrag[2] = u8.v;
            }

            f32x4 acc0 = {0.f, 0.f, 0.f, 0.f};
            f32x4 acc1 = {0.f, 0.f, 0.f, 0.f};
#pragma unroll
            for (int k3 = 0; k3 < 3; ++k3) {
                acc0 = MFMA16(a1[0][k3], bfrag[k3], acc0);
                acc1 = MFMA16(a1[1][k3], bfrag[k3], acc1);
            }
            float r0[4], r1[4];
#pragma unroll
            for (int r = 0; r < 4; ++r) {
                r0[r] = fmaxf(acc0[r] + bias[0][r], 0.f);
                r1[r] = fmaxf(acc1[r] + bias[1][r], 0.f);
            }
            *(uint2*)(&interm[p * 40 + g * 4])      = make_uint2(cvtpk(r0[0], r0[1]), cvtpk(r0[2], r0[3]));
            *(uint2*)(&interm[p * 40 + 16 + g * 4]) = make_uint2(cvtpk(r1[0], r1[1]), cvtpk(r1[2], r1[3]));
        }
    }
    __syncthreads();

    // =================== phase 2: prim conv, row-split by wave ===================
    f32x4 acc[2][3];
#pragma unroll
    for (int m = 0; m < 2; ++m)
#pragma unroll
        for (int nt = 0; nt < 3; ++nt)
            acc[m][nt] = (f32x4){0.f, 0.f, 0.f, 0.f};
    {
        int abase[3];   // byte base per nt: pos0*80 + g*16
#pragma unroll
        for (int nt = 0; nt < 3; ++nt) {
            int p2 = nt * 16 + col;
            int xw = p2 / 6, yh = p2 - xw * 6;
            int pos0 = (p2 < 36) ? (yh * 40 + xw * 2) : 0;
            abase[nt] = pos0 * 80 + g * 16;
        }
        const bf16x8* w3p = (const bf16x8*)w3f;
        const char* ib = (const char*)interm;

        for (int rr = 0; rr < 2; ++rr) {
            const int ky = 2 * w + rr;
            const bf16x8* wrow = w3p + (ky * 9) * 128;
            const char* B0 = ib + abase[0] + ky * 1600;
            const char* B1 = ib + abase[1] + ky * 1600;
            const char* B2 = ib + abase[2] + ky * 1600;
            __builtin_amdgcn_s_setprio(1);
#pragma unroll
            for (int kx = 0; kx < 9; ++kx) {
                bf16x8 a0  = wrow[kx * 128 + lane];
                bf16x8 a1v = wrow[kx * 128 + 64 + lane];
                bf16x8 b0 = *(const bf16x8*)(B0 + kx * 80);
                bf16x8 b1 = *(const bf16x8*)(B1 + kx * 80);
                bf16x8 b2 = *(const bf16x8*)(B2 + kx * 80);
                acc[0][0] = MFMA16(a0, b0, acc[0][0]);
                acc[1][0] = MFMA16(a1v, b0, acc[1][0]);
                acc[0][1] = MFMA16(a0, b1, acc[0][1]);
                acc[1][1] = MFMA16(a1v, b1, acc[1][1]);
                acc[0][2] = MFMA16(a0, b2, acc[0][2]);
                acc[1][2] = MFMA16(a1v, b2, acc[1][2]);
            }
            __builtin_amdgcn_s_setprio(0);
        }
        // row 8 leftovers: w0:{0,1} w1:{2,3} w2:{4,5} w3:{6,7,8}
        {
            const bf16x8* wrow = w3p + 72 * 128;
            const char* B0 = ib + abase[0] + 12800;
            const char* B1 = ib + abase[1] + 12800;
            const char* B2 = ib + abase[2] + 12800;
            int kx0 = 2 * w;
            int nkx = (w == 3) ? 3 : 2;
            __builtin_amdgcn_s_setprio(1);
#pragma unroll 3
            for (int q = 0; q < nkx; ++q) {
                int kx = kx0 + q;
                bf16x8 a0  = wrow[kx * 128 + lane];
                bf16x8 a1v = wrow[kx * 128 + 64 + lane];
                bf16x8 b0 = *(const bf16x8*)(B0 + kx * 80);
                bf16x8 b1 = *(const bf16x8*)(B1 + kx * 80);
                bf16x8 b2 = *(const bf16x8*)(B2 + kx * 80);
                acc[0][0] = MFMA16(a0, b0, acc[0][0]);
                acc[1][0] = MFMA16(a1v, b0, acc[1][0]);
                acc[0][1] = MFMA16(a0, b1, acc[0][1]);
                acc[1][1] = MFMA16(a1v, b1, acc[1][1]);
                acc[0][2] = MFMA16(a0, b2, acc[0][2]);
                acc[1][2] = MFMA16(a1v, b2, acc[1][2]);
            }
            __builtin_amdgcn_s_setprio(0);
        }
    }
    __syncthreads();
    // ---- cross-wave reduction (f32x4 overlay on interm) ----
    f32x4* rp = (f32x4*)&interm[0];
    {
#pragma unroll
        for (int m = 0; m < 2; ++m)
#pragma unroll
            for (int nt = 0; nt < 3; ++nt)
                rp[(w * 6 + m * 3 + nt) * 64 + lane] = acc[m][nt];
    }
    __syncthreads();
    for (int idx = t; idx < 384; idx += 256) {
        int tile = idx >> 6, ls = idx & 63;
        f32x4 s = rp[tile * 64 + ls];
#pragma unroll
        for (int ww = 1; ww < 4; ++ww)
            s += rp[(ww * 6 + tile) * 64 + ls];
        int m = tile / 3, nt = tile - m * 3;
        int p2 = nt * 16 + (ls & 15);
        if (p2 < 36) {
            int gr = ls >> 4;
#pragma unroll
            for (int r = 0; r < 4; ++r) {
                int oc = m * 16 + gr * 4 + r;
                caps[(b * 8 + d) * 1152 + oc * 36 + p2] = fmaxf(s[r] + pb[oc], 0.f);
            }
        }
    }
}

// ---------------------------------------------------------------------------
// K2: routing (R9 measured-best). 576 threads, ~50.3 KB LDS -> 3 blocks/CU.
// ---------------------------------------------------------------------------
#define USB 1160   // u_bf row stride (bf16)
#define CHS 584    // chalf row stride (bf16)

__global__ __launch_bounds__(576, 8) void k_route(
    const float* __restrict__ caps,  // [1024,8,1152]
    const unsigned short* __restrict__ Wbf,  // [1152,8,16] bf16
    const float* __restrict__ Wb,    // [1152,16]
    const float* __restrict__ ow,    // [10,10,16,1]
    const float* __restrict__ ob,    // [10]
    float* __restrict__ out)         // [1024,10]
{
    __shared__ __align__(16) unsigned short u_bf[16 * USB];   // 37,120 B
    __shared__ __align__(16) unsigned short chalf[10 * CHS];  // 11,680 B (+scratch overlay)
    __shared__ __align__(16) float vv[16 * 12];
    __shared__ float ss[160];
    __shared__ float red2[16];

    const int t = threadIdx.x;
    const int lane = t & 63, wv = t >> 6;
    const int g = lane >> 4, col = lane & 15;
    const int b = blockIdx.x;
    const int n0 = 2 * t;

    // ---- stage A: u[f][n] -> bf16 (W streamed as bf16) ----
    {
        const int nl = t >> 2, fq = t & 3;
        for (int base = 0; base < 1152; base += 144) {
            int n = base + nl;
            float cv[8];
#pragma unroll
            for (int e = 0; e < 8; ++e) cv[e] = caps[(b * 8 + e) * 1152 + n];
            float4 a4 = ((const float4*)(Wb + n * 16))[fq];
#pragma unroll
            for (int e = 0; e < 8; ++e) {
                uint2 wp = *(const uint2*)(&Wbf[n * 128 + e * 16 + fq * 4]);
                float w0 = __builtin_bit_cast(float, wp.x << 16);
                float w1 = __builtin_bit_cast(float, wp.x & 0xffff0000u);
                float w2 = __builtin_bit_cast(float, wp.y << 16);
                float w3 = __builtin_bit_cast(float, wp.y & 0xffff0000u);
                a4.x += cv[e] * w0; a4.y += cv[e] * w1;
                a4.z += cv[e] * w2; a4.w += cv[e] * w3;
            }
            u_bf[(fq * 4 + 0) * USB + n] = f2bf(a4.x);
            u_bf[(fq * 4 + 1) * USB + n] = f2bf(a4.y);
            u_bf[(fq * 4 + 2) * USB + n] = f2bf(a4.z);
            u_bf[(fq * 4 + 3) * USB + n] = f2bf(a4.w);
        }
    }
    float breg[2][10];
#pragma unroll
    for (int s = 0; s < 2; ++s)
#pragma unroll
        for (int jj = 0; jj < 10; ++jj) breg[s][jj] = 0.f;
    __syncthreads();

    const int jrow = (col < 10) ? col : 9;
    const int hmine = (t >= 288);
    const int nh = 2 * t - 576 * hmine;

    for (int iter = 0; iter < 3; ++iter) {
        // ---- softmax over j for n0,n0+1 -> packed bf16 pairs (registers) ----
        unsigned pk[10];
        {
            float cv2[2][10];
#pragma unroll
            for (int s = 0; s < 2; ++s) {
                float m = breg[s][0];
#pragma unroll
                for (int jj = 1; jj < 10; ++jj) m = fmaxf(m, breg[s][jj]);
                float sum = 0.f;
#pragma unroll
                for (int jj = 0; jj < 10; ++jj) { cv2[s][jj] = __expf(breg[s][jj] - m); sum += cv2[s][jj]; }
                float inv = 1.f / sum;
#pragma unroll
                for (int jj = 0; jj < 10; ++jj) cv2[s][jj] *= inv;
            }
#pragma unroll
            for (int jj = 0; jj < 10; ++jj)
                pk[jj] = cvtpk(cv2[0][jj], cv2[1][jj]);
        }

        // ---- stage B+C over two n-halves; sp accumulates in registers ----
        f32x4 sp = {0.f, 0.f, 0.f, 0.f};
#pragma unroll
        for (int h = 0; h < 2; ++h) {
            if (hmine == h) {
#pragma unroll
                for (int jj = 0; jj < 10; ++jj)
                    *(unsigned*)(&chalf[jj * CHS + nh]) = pk[jj];
            }
            __syncthreads();
#pragma unroll
            for (int mf = 0; mf < 2; ++mf) {
                int nk = wv * 64 + mf * 32 + g * 8;
                bf16x8 af = *(const bf16x8*)(&chalf[jrow * CHS + nk]);
                bf16x8 bf = *(const bf16x8*)(&u_bf[col * USB + h * 576 + nk]);
                sp = MFMA16(af, bf, sp);
            }
            __syncthreads();
        }
        // ---- partials -> scratch (overlays chalf) ----
        float* scratch = (float*)chalf;
        *(f32x4*)(&scratch[(wv * 64 + lane) * 4]) = sp;
        __syncthreads();
        if (t < 160) {
            int j = t >> 4, f = t & 15;
            int li = ((j >> 2) * 16 + f) * 4 + (j & 3);
            float s = 0.f;
#pragma unroll
            for (int ww = 0; ww < 9; ++ww) s += scratch[ww * 256 + li];
            ss[j * 16 + f] = s;
        }
        __syncthreads();
        if (t < 16) {
            float sv[10], l2 = 0.f, l1 = 0.f;
#pragma unroll
            for (int jj = 0; jj < 10; ++jj) {
                sv[jj] = ss[jj * 16 + t];
                l2 += sv[jj] * sv[jj]; l1 += fabsf(sv[jj]);
            }
            l2 = sqrtf(l2);
            float scale = l2 / (1.f + l2) / l1;
#pragma unroll
            for (int jj = 0; jj < 10; ++jj) vv[t * 12 + jj] = sv[jj] * scale;
        }
        __syncthreads();
        if (iter < 2) {
#pragma unroll
            for (int f = 0; f < 16; ++f) {
                unsigned pair = *(const unsigned*)(&u_bf[f * USB + n0]);
                float ux = __builtin_bit_cast(float, pair << 16);
                float uy = __builtin_bit_cast(float, pair & 0xffff0000u);
                f32x4 v0 = *(const f32x4*)(&vv[f * 12]);
                f32x4 v1 = *(const f32x4*)(&vv[f * 12 + 4]);
                float2 v2 = *(const float2*)(&vv[f * 12 + 8]);
                breg[0][0] += ux * v0.x; breg[1][0] += uy * v0.x;
                breg[0][1] += ux * v0.y; breg[1][1] += uy * v0.y;
                breg[0][2] += ux * v0.z; breg[1][2] += uy * v0.z;
                breg[0][3] += ux * v0.w; breg[1][3] += uy * v0.w;
                breg[0][4] += ux * v1.x; breg[1][4] += uy * v1.x;
                breg[0][5] += ux * v1.y; breg[1][5] += uy * v1.y;
                breg[0][6] += ux * v1.z; breg[1][6] += uy * v1.z;
                breg[0][7] += ux * v1.w; breg[1][7] += uy * v1.w;
                breg[0][8] += ux * v2.x; breg[1][8] += uy * v2.x;
                breg[0][9] += ux * v2.y; breg[1][9] += uy * v2.y;
            }
        }
        __syncthreads();
    }

    // ---- output head + softmax ----
    if (t < 10) {
        float l = ob[t];
#pragma unroll
        for (int i2 = 0; i2 < 10; ++i2)
#pragma unroll
            for (int ff = 0; ff < 16; ++ff)
                l += vv[ff * 12 + i2] * ow[t * 160 + i2 * 16 + ff];
        red2[t] = l;
    }
    __syncthreads();
    if (t == 0) {
        float m = -1e30f;
        for (int o = 0; o < 10; ++o) m = fmaxf(m, red2[o]);
        float sum = 0.f; float e[10];
        for (int o = 0; o < 10; ++o) { e[o] = __expf(red2[o] - m); sum += e[o]; }
        float inv = 1.f / sum;
        for (int o = 0; o < 10; ++o) out[b * 10 + o] = e[o] * inv;
    }
}

extern "C" void kernel_launch(void* const* d_in, const int* in_sizes, int n_in,
                              void* d_out, int out_size, void* d_ws, size_t ws_size,
                              hipStream_t stream) {
    const float* x     = (const float*)d_in[0];
    const float* c1w   = (const float*)d_in[1];
    const float* c1b   = (const float*)d_in[2];
    const float* pw    = (const float*)d_in[3];
    const float* pb    = (const float*)d_in[4];
    const float* digW  = (const float*)d_in[5];
    const float* digWb = (const float*)d_in[6];
    const float* outw  = (const float*)d_in[7];
    const float* outb  = (const float*)d_in[8];
    float* out = (float*)d_out;

    float* caps = (float*)d_ws;
    unsigned short* w1f = (unsigned short*)((char*)d_ws + CAPS_BYTES);
    unsigned short* w3f = w1f + A1F_ELEMS;
    unsigned short* wbf = w3f + W3F_ELEMS;

    k_prep<<<dim3(996), dim3(256), 0, stream>>>(c1w, pw, digW, w1f, w3f, wbf);
    k_conv<<<dim3(8192), dim3(256), 0, stream>>>(x, c1b, pb, w1f, w3f, caps);
    k_route<<<dim3(1024), dim3(576), 0, stream>>>(caps, wbf, digWb, outw, outb, out);
}